// Round 1
// baseline (4712.457 us; speedup 1.0000x reference)
//
#include <hip/hip_runtime.h>
#include <hip/hip_bf16.h>

#define B_ 32
#define T_ 64
#define H_ 1024
#define G3 3072
#define V_ 32000
#define M_ 2048   // B_*T_

typedef __attribute__((ext_vector_type(8))) short s16x8;
typedef __attribute__((ext_vector_type(4))) float f32x4;
typedef __bf16 bf16x8 __attribute__((ext_vector_type(8)));
// NOTE: if __builtin_amdgcn_mfma_f32_16x16x32_bf16 rejects bf16x8, fallback is s16x8 args directly.

__device__ inline unsigned short f2bf(float f) {
    union { float f; unsigned int u; } v; v.f = f;
    unsigned int u = v.u;
    return (unsigned short)((u + 0x7FFFu + ((u >> 16) & 1u)) >> 16);
}

__global__ void cast_f32_bf16(const float* __restrict__ src, unsigned short* __restrict__ dst, int n) {
    int i = (blockIdx.x * blockDim.x + threadIdx.x) * 4;
    int stride = gridDim.x * blockDim.x * 4;
    for (; i < n; i += stride) {
        float4 v = *(const float4*)(src + i);
        ushort4 o;
        o.x = f2bf(v.x); o.y = f2bf(v.y); o.z = f2bf(v.z); o.w = f2bf(v.w);
        *(ushort4*)(dst + i) = o;
    }
}

__global__ void embed_relu(const int* __restrict__ target, const float* __restrict__ emb,
                           unsigned short* __restrict__ x) {
    int m = blockIdx.x;           // 0..2047  (m = b*64 + t)
    int b = m >> 6, t = m & 63;
    int tok = (t == 0) ? 1 : target[b * T_ + t - 1];   // SOS=1, else teacher forcing
    const float* row = emb + (size_t)tok * H_;
    int k = threadIdx.x * 4;
    float4 v = *(const float4*)(row + k);
    ushort4 o;
    o.x = f2bf(fmaxf(v.x, 0.f)); o.y = f2bf(fmaxf(v.y, 0.f));
    o.z = f2bf(fmaxf(v.z, 0.f)); o.w = f2bf(fmaxf(v.w, 0.f));
    *(ushort4*)(x + (size_t)m * H_ + k) = o;
}

// C[m][n] = sum_k A[m][k]*B[n][k] + bias[n].  A:[M,K] bf16, B:[N,K] bf16, C f32.
// 128x128 tile, BK=32, 4 waves (2x2), 16x16x32 bf16 MFMA.
#define BK 32
#define LDP 40   // padded LDS row stride (shorts): 80B -> 2-way bank aliasing (free)

__global__ __launch_bounds__(256) void gemm_bias(
    const unsigned short* __restrict__ A,
    const unsigned short* __restrict__ Bm,
    const float* __restrict__ bias,
    float* __restrict__ C,
    int N, int K)
{
    __shared__ unsigned short As[128 * LDP];
    __shared__ unsigned short Bs[128 * LDP];
    int n0 = blockIdx.x * 128, m0 = blockIdx.y * 128;
    int tid = threadIdx.x;
    int lane = tid & 63, wv = tid >> 6;
    int wr = wv >> 1, wc = wv & 1;

    f32x4 acc[4][4] = {};

    int kq = (lane >> 4) * 8;          // k-offset of this lane's 8-elem chunk
    int rA = wr * 64 + (lane & 15);    // fragment row base (m within tile)
    int rB = wc * 64 + (lane & 15);    // fragment row base (n within tile)

    for (int k0 = 0; k0 < K; k0 += BK) {
        // stage 128x32 bf16 tiles of A and B (2 passes of 256 threads x 8 elems)
#pragma unroll
        for (int p = 0; p < 2; ++p) {
            int idx = p * 256 + tid;
            int row = idx >> 2, kof = (idx & 3) * 8;
            *(s16x8*)(As + row * LDP + kof) = *(const s16x8*)(A + (size_t)(m0 + row) * K + k0 + kof);
            *(s16x8*)(Bs + row * LDP + kof) = *(const s16x8*)(Bm + (size_t)(n0 + row) * K + k0 + kof);
        }
        __syncthreads();

        s16x8 af[4], bf[4];
#pragma unroll
        for (int i = 0; i < 4; ++i) {
            af[i] = *(const s16x8*)(As + (rA + i * 16) * LDP + kq);
            bf[i] = *(const s16x8*)(Bs + (rB + i * 16) * LDP + kq);
        }
#pragma unroll
        for (int mf = 0; mf < 4; ++mf)
#pragma unroll
            for (int nf = 0; nf < 4; ++nf)
                acc[mf][nf] = __builtin_amdgcn_mfma_f32_16x16x32_bf16(
                    __builtin_bit_cast(bf16x8, af[mf]),
                    __builtin_bit_cast(bf16x8, bf[nf]),
                    acc[mf][nf], 0, 0, 0);
        __syncthreads();
    }

    // epilogue: D row=(lane>>4)*4+reg, col=lane&15  [verified layout]
#pragma unroll
    for (int nf = 0; nf < 4; ++nf) {
        int col = n0 + wc * 64 + nf * 16 + (lane & 15);
        float bv = bias[col];
#pragma unroll
        for (int mf = 0; mf < 4; ++mf) {
            int mbase = m0 + wr * 64 + mf * 16 + (lane >> 4) * 4;
#pragma unroll
            for (int r = 0; r < 4; ++r)
                C[(size_t)(mbase + r) * N + col] = acc[mf][nf][r] + bv;
        }
    }
}

// one GRU step: h_next = GRU(h_prev, xg[:,t,:]); also writes hs[:,t,:] as bf16
__global__ __launch_bounds__(256) void gru_step(
    const float* __restrict__ h_prev,   // [32,1024]
    float* __restrict__ h_next,         // [32,1024]
    const float* __restrict__ Whh,      // [3072,1024]
    const float* __restrict__ b_hh,     // [3072]
    const float* __restrict__ xg,       // [32,64,3072] (b_ih already added)
    unsigned short* __restrict__ hs,    // [32,64,1024] bf16
    int t)
{
    int tid = threadIdx.x;
    int b = tid & 31, jl = tid >> 5;
    int j = blockIdx.x * 8 + jl;
    const float* hrow = h_prev + b * H_;
    const float* w0 = Whh + (size_t)j * H_;
    const float* w1 = Whh + (size_t)(H_ + j) * H_;
    const float* w2 = Whh + (size_t)(2 * H_ + j) * H_;
    float ar = 0.f, az = 0.f, an = 0.f;
    for (int k = 0; k < H_; k += 4) {
        float4 hv = *(const float4*)(hrow + k);
        float4 v0 = *(const float4*)(w0 + k);
        float4 v1 = *(const float4*)(w1 + k);
        float4 v2 = *(const float4*)(w2 + k);
        ar += hv.x * v0.x + hv.y * v0.y + hv.z * v0.z + hv.w * v0.w;
        az += hv.x * v1.x + hv.y * v1.y + hv.z * v1.z + hv.w * v1.w;
        an += hv.x * v2.x + hv.y * v2.y + hv.z * v2.z + hv.w * v2.w;
    }
    ar += b_hh[j]; az += b_hh[H_ + j]; an += b_hh[2 * H_ + j];
    const float* xgr = xg + (size_t)b * T_ * G3 + (size_t)t * G3;
    float xr = xgr[j], xz = xgr[H_ + j], xn = xgr[2 * H_ + j];
    float r = 1.f / (1.f + __expf(-(xr + ar)));
    float z = 1.f / (1.f + __expf(-(xz + az)));
    float n = tanhf(xn + r * an);
    float hnew = (1.f - z) * n + z * hrow[j];
    h_next[b * H_ + j] = hnew;
    hs[(size_t)b * T_ * H_ + (size_t)t * H_ + j] = f2bf(hnew);
}

__global__ __launch_bounds__(256) void log_softmax_inplace(float* __restrict__ out) {
    int m = blockIdx.x;
    float* row = out + (size_t)m * V_;
    int tid = threadIdx.x;
    __shared__ float sbuf[8];
    // pass 1: row max
    float mx = -1e30f;
    for (int i = tid * 4; i < V_; i += 1024) {
        float4 v = *(const float4*)(row + i);
        mx = fmaxf(mx, fmaxf(fmaxf(v.x, v.y), fmaxf(v.z, v.w)));
    }
    for (int o = 32; o > 0; o >>= 1) mx = fmaxf(mx, __shfl_xor(mx, o));
    int wv = tid >> 6, lane = tid & 63;
    if (lane == 0) sbuf[wv] = mx;
    __syncthreads();
    mx = fmaxf(fmaxf(sbuf[0], sbuf[1]), fmaxf(sbuf[2], sbuf[3]));
    // pass 2: sum exp
    float s = 0.f;
    for (int i = tid * 4; i < V_; i += 1024) {
        float4 v = *(const float4*)(row + i);
        s += __expf(v.x - mx) + __expf(v.y - mx) + __expf(v.z - mx) + __expf(v.w - mx);
    }
    for (int o = 32; o > 0; o >>= 1) s += __shfl_xor(s, o);
    __syncthreads();
    if (lane == 0) sbuf[4 + wv] = s;
    __syncthreads();
    float lse = mx + __logf(sbuf[4] + sbuf[5] + sbuf[6] + sbuf[7]);
    // pass 3: subtract
    for (int i = tid * 4; i < V_; i += 1024) {
        float4 v = *(const float4*)(row + i);
        v.x -= lse; v.y -= lse; v.z -= lse; v.w -= lse;
        *(float4*)(row + i) = v;
    }
}

__global__ void copy_f32(const float* __restrict__ src, float* __restrict__ dst, int n) {
    int i = blockIdx.x * blockDim.x + threadIdx.x;
    if (i < n) dst[i] = src[i];
}

extern "C" void kernel_launch(void* const* d_in, const int* in_sizes, int n_in,
                              void* d_out, int out_size, void* d_ws, size_t ws_size,
                              hipStream_t stream) {
    const float* enc_hidden = (const float*)d_in[1];   // [1,32,1024]
    const int*   target     = (const int*)d_in[2];     // [32,64]
    const float* embedding  = (const float*)d_in[3];   // [32000,1024]
    const float* W_ih       = (const float*)d_in[4];   // [3072,1024]
    const float* W_hh       = (const float*)d_in[5];   // [3072,1024]
    const float* b_ih       = (const float*)d_in[6];   // [3072]
    const float* b_hh       = (const float*)d_in[7];   // [3072]
    const float* out_W      = (const float*)d_in[8];   // [32000,1024]
    const float* out_b      = (const float*)d_in[9];   // [32000]
    float* out = (float*)d_out;

    char* ws = (char*)d_ws;
    float*          xg   = (float*)(ws);                        // 25,165,824 B  [2048,3072] f32
    unsigned short* xb   = (unsigned short*)(ws + 25165824);    //  4,194,304 B  [2048,1024] bf16
    unsigned short* hsb  = (unsigned short*)(ws + 29360128);    //  4,194,304 B  [2048,1024] bf16
    unsigned short* wihb = (unsigned short*)(ws + 33554432);    //  6,291,456 B
    unsigned short* owb  = (unsigned short*)(ws + 39845888);    // 65,536,000 B
    float*          h0b  = (float*)(ws + 105381888);            //    131,072 B
    float*          h1b  = (float*)(ws + 105512960);            //    131,072 B

    cast_f32_bf16<<<512, 256, 0, stream>>>(W_ih, wihb, G3 * H_);
    cast_f32_bf16<<<2048, 256, 0, stream>>>(out_W, owb, V_ * H_);
    embed_relu<<<M_, 256, 0, stream>>>(target, embedding, xb);

    // xg = relu(emb) @ W_ih^T + b_ih   [2048 x 3072]
    gemm_bias<<<dim3(G3 / 128, M_ / 128), 256, 0, stream>>>(xb, wihb, b_ih, xg, G3, H_);

    // sequential GRU scan (64 steps), h double-buffered in ws
    const float* hp = enc_hidden;
    for (int t = 0; t < T_; ++t) {
        float* hn = (t & 1) ? h1b : h0b;
        gru_step<<<128, 256, 0, stream>>>(hp, hn, W_hh, b_hh, xg, hsb, t);
        hp = hn;
    }

    // logits = hs @ out_W^T + out_b  -> d_out, then in-place log_softmax
    gemm_bias<<<dim3(V_ / 128, M_ / 128), 256, 0, stream>>>(hsb, owb, out_b, out, V_, H_);
    log_softmax_inplace<<<M_, 256, 0, stream>>>(out);

    // h_last -> tail of d_out
    copy_f32<<<128, 256, 0, stream>>>(hp, out + (size_t)M_ * V_, B_ * H_);
}

// Round 2
// 1226.143 us; speedup vs baseline: 3.8433x; 3.8433x over previous
//
#include <hip/hip_runtime.h>
#include <hip/hip_bf16.h>

#define B_ 32
#define T_ 64
#define H_ 1024
#define G3 3072
#define V_ 32000
#define M_ 2048   // B_*T_

typedef __attribute__((ext_vector_type(8))) short s16x8;
typedef __attribute__((ext_vector_type(4))) float f32x4;
typedef __bf16 bf16x8 __attribute__((ext_vector_type(8)));

__device__ inline unsigned short f2bf(float f) {
    union { float f; unsigned int u; } v; v.f = f;
    unsigned int u = v.u;
    return (unsigned short)((u + 0x7FFFu + ((u >> 16) & 1u)) >> 16);
}

__global__ void cast_f32_bf16(const float* __restrict__ src, unsigned short* __restrict__ dst, int n) {
    int i = (blockIdx.x * blockDim.x + threadIdx.x) * 4;
    int stride = gridDim.x * blockDim.x * 4;
    for (; i < n; i += stride) {
        float4 v = *(const float4*)(src + i);
        ushort4 o;
        o.x = f2bf(v.x); o.y = f2bf(v.y); o.z = f2bf(v.z); o.w = f2bf(v.w);
        *(ushort4*)(dst + i) = o;
    }
}

__global__ void embed_relu(const int* __restrict__ target, const float* __restrict__ emb,
                           unsigned short* __restrict__ x) {
    int m = blockIdx.x;           // m = b*64 + t
    int b = m >> 6, t = m & 63;
    int tok = (t == 0) ? 1 : target[b * T_ + t - 1];
    const float* row = emb + (size_t)tok * H_;
    int k = threadIdx.x * 4;
    float4 v = *(const float4*)(row + k);
    ushort4 o;
    o.x = f2bf(fmaxf(v.x, 0.f)); o.y = f2bf(fmaxf(v.y, 0.f));
    o.z = f2bf(fmaxf(v.z, 0.f)); o.w = f2bf(fmaxf(v.w, 0.f));
    *(ushort4*)(x + (size_t)m * H_ + k) = o;
}

__global__ void init_h(const float* __restrict__ enc_hidden,
                       float* __restrict__ hf, unsigned short* __restrict__ hb) {
    int i = blockIdx.x * blockDim.x + threadIdx.x;
    if (i < B_ * H_) {
        float v = enc_hidden[i];
        hf[i] = v;
        hb[i] = f2bf(v);
    }
}

// ---------------- GEMM: C[m][n] = sum_k A[m][k]*B[n][k] + bias[n] ----------------
#define BK 32
#define LDP 34   // row stride (shorts): 68B = 17 banks, gcd(17,32)=1 -> uniform 2-way (free)

__global__ __launch_bounds__(256) void gemm_bias(
    const unsigned short* __restrict__ A,
    const unsigned short* __restrict__ Bm,
    const float* __restrict__ bias,
    float* __restrict__ C,
    int N, int K)
{
    __shared__ unsigned short As[128 * LDP];
    __shared__ unsigned short Bs[128 * LDP];
    int n0 = blockIdx.x * 128, m0 = blockIdx.y * 128;
    int tid = threadIdx.x;
    int lane = tid & 63, wv = tid >> 6;
    int wr = wv >> 1, wc = wv & 1;

    f32x4 acc[4][4] = {};

    int kq = (lane >> 4) * 8;
    int rA = wr * 64 + (lane & 15);
    int rB = wc * 64 + (lane & 15);

    for (int k0 = 0; k0 < K; k0 += BK) {
#pragma unroll
        for (int p = 0; p < 2; ++p) {
            int idx = p * 256 + tid;
            int row = idx >> 2, kof = (idx & 3) * 8;
            *(s16x8*)(As + row * LDP + kof) = *(const s16x8*)(A + (size_t)(m0 + row) * K + k0 + kof);
            *(s16x8*)(Bs + row * LDP + kof) = *(const s16x8*)(Bm + (size_t)(n0 + row) * K + k0 + kof);
        }
        __syncthreads();

        s16x8 af[4], bf[4];
#pragma unroll
        for (int i = 0; i < 4; ++i) {
            af[i] = *(const s16x8*)(As + (rA + i * 16) * LDP + kq);
            bf[i] = *(const s16x8*)(Bs + (rB + i * 16) * LDP + kq);
        }
#pragma unroll
        for (int mf = 0; mf < 4; ++mf)
#pragma unroll
            for (int nf = 0; nf < 4; ++nf)
                acc[mf][nf] = __builtin_amdgcn_mfma_f32_16x16x32_bf16(
                    __builtin_bit_cast(bf16x8, af[mf]),
                    __builtin_bit_cast(bf16x8, bf[nf]),
                    acc[mf][nf], 0, 0, 0);
        __syncthreads();
    }

#pragma unroll
    for (int nf = 0; nf < 4; ++nf) {
        int col = n0 + wc * 64 + nf * 16 + (lane & 15);
        float bv = bias[col];
#pragma unroll
        for (int mf = 0; mf < 4; ++mf) {
            int mbase = m0 + wr * 64 + mf * 16 + (lane >> 4) * 4;
#pragma unroll
            for (int r = 0; r < 4; ++r)
                C[(size_t)(mbase + r) * N + col] = acc[mf][nf][r] + bv;
        }
    }
}

// ---------------- fused GRU step: one wave per 16x16 (batch x j) tile, 3 gates ----------------
__global__ __launch_bounds__(64) void gru_step_mfma(
    const unsigned short* __restrict__ hb,   // h_prev bf16 [32,1024]
    const float* __restrict__ hf,            // h_prev f32  [32,1024]
    unsigned short* __restrict__ hb_next,
    float* __restrict__ hf_next,
    const unsigned short* __restrict__ Whhb, // [3072,1024] bf16
    const float* __restrict__ b_hh,          // [3072]
    const float* __restrict__ xg,            // [2048,3072], row m=b*64+t (b_ih added)
    unsigned short* __restrict__ hs,         // [2048,1024] bf16
    int t)
{
    int lane = threadIdx.x;
    int gw = blockIdx.x;          // 0..127
    int rt = gw & 1;              // batch tile
    int ct = gw >> 1;             // j tile (0..63)
    int col = ct * 16 + (lane & 15);
    int rowb = rt * 16 + (lane & 15);
    int kq = (lane >> 4) * 8;

    // bias -> accumulator init (bias depends only on col = lane&15, same across regs)
    float br = b_hh[col], bz = b_hh[H_ + col], bn = b_hh[2 * H_ + col];
    f32x4 accr = {br, br, br, br};
    f32x4 accz = {bz, bz, bz, bz};
    f32x4 accn = {bn, bn, bn, bn};

    const unsigned short* ha = hb + (size_t)rowb * H_ + kq;
    const unsigned short* wr_ = Whhb + (size_t)col * H_ + kq;
    const unsigned short* wz_ = Whhb + (size_t)(H_ + col) * H_ + kq;
    const unsigned short* wn_ = Whhb + (size_t)(2 * H_ + col) * H_ + kq;

#pragma unroll 4
    for (int k0 = 0; k0 < H_; k0 += 32) {
        s16x8 af = *(const s16x8*)(ha + k0);
        s16x8 fr = *(const s16x8*)(wr_ + k0);
        s16x8 fz = *(const s16x8*)(wz_ + k0);
        s16x8 fn = *(const s16x8*)(wn_ + k0);
        bf16x8 a = __builtin_bit_cast(bf16x8, af);
        accr = __builtin_amdgcn_mfma_f32_16x16x32_bf16(a, __builtin_bit_cast(bf16x8, fr), accr, 0, 0, 0);
        accz = __builtin_amdgcn_mfma_f32_16x16x32_bf16(a, __builtin_bit_cast(bf16x8, fz), accz, 0, 0, 0);
        accn = __builtin_amdgcn_mfma_f32_16x16x32_bf16(a, __builtin_bit_cast(bf16x8, fn), accn, 0, 0, 0);
    }

    // epilogue: C row=(lane>>4)*4+r, col=lane&15
    int b0 = rt * 16 + (lane >> 4) * 4;
#pragma unroll
    for (int r = 0; r < 4; ++r) {
        int b = b0 + r;
        const float* xrow = xg + ((size_t)b * T_ + t) * G3;
        float xr = xrow[col], xz = xrow[H_ + col], xn = xrow[2 * H_ + col];
        float rr = 1.f / (1.f + __expf(-(xr + accr[r])));
        float zz = 1.f / (1.f + __expf(-(xz + accz[r])));
        float nn = tanhf(xn + rr * accn[r]);
        float hold = hf[b * H_ + col];
        float hnew = (1.f - zz) * nn + zz * hold;
        hf_next[b * H_ + col] = hnew;
        unsigned short h16 = f2bf(hnew);
        hb_next[b * H_ + col] = h16;
        hs[((size_t)b * T_ + t) * H_ + col] = h16;
    }
}

// ---------------- online log_softmax: 2 reads + 1 write ----------------
__global__ __launch_bounds__(256) void log_softmax_inplace(float* __restrict__ out) {
    int m = blockIdx.x;
    float* row = out + (size_t)m * V_;
    int tid = threadIdx.x;
    __shared__ float sm[4], ss[4];

    float mx = -1e30f, s = 0.f;
    for (int i = tid * 4; i < V_; i += 1024) {
        float4 v = *(const float4*)(row + i);
        float lm = fmaxf(fmaxf(v.x, v.y), fmaxf(v.z, v.w));
        float ns = __expf(v.x - lm) + __expf(v.y - lm) + __expf(v.z - lm) + __expf(v.w - lm);
        if (lm > mx) { s = s * __expf(mx - lm) + ns; mx = lm; }
        else          { s += ns * __expf(lm - mx); }
    }
    // wave reduce (m,s)
    for (int o = 32; o > 0; o >>= 1) {
        float om = __shfl_xor(mx, o), os = __shfl_xor(s, o);
        float nm = fmaxf(mx, om);
        s = s * __expf(mx - nm) + os * __expf(om - nm);
        mx = nm;
    }
    int wv = tid >> 6, lane = tid & 63;
    if (lane == 0) { sm[wv] = mx; ss[wv] = s; }
    __syncthreads();
    float fm = fmaxf(fmaxf(sm[0], sm[1]), fmaxf(sm[2], sm[3]));
    float fs = ss[0] * __expf(sm[0] - fm) + ss[1] * __expf(sm[1] - fm)
             + ss[2] * __expf(sm[2] - fm) + ss[3] * __expf(sm[3] - fm);
    float lse = fm + __logf(fs);

    for (int i = tid * 4; i < V_; i += 1024) {
        float4 v = *(const float4*)(row + i);
        v.x -= lse; v.y -= lse; v.z -= lse; v.w -= lse;
        *(float4*)(row + i) = v;
    }
}

__global__ void copy_f32(const float* __restrict__ src, float* __restrict__ dst, int n) {
    int i = blockIdx.x * blockDim.x + threadIdx.x;
    if (i < n) dst[i] = src[i];
}

extern "C" void kernel_launch(void* const* d_in, const int* in_sizes, int n_in,
                              void* d_out, int out_size, void* d_ws, size_t ws_size,
                              hipStream_t stream) {
    const float* enc_hidden = (const float*)d_in[1];   // [1,32,1024]
    const int*   target     = (const int*)d_in[2];     // [32,64]
    const float* embedding  = (const float*)d_in[3];   // [32000,1024]
    const float* W_ih       = (const float*)d_in[4];   // [3072,1024]
    const float* W_hh       = (const float*)d_in[5];   // [3072,1024]
    const float* b_ih       = (const float*)d_in[6];   // [3072]
    const float* b_hh       = (const float*)d_in[7];   // [3072]
    const float* out_W      = (const float*)d_in[8];   // [32000,1024]
    const float* out_b      = (const float*)d_in[9];   // [32000]
    float* out = (float*)d_out;

    char* ws = (char*)d_ws;
    float*          xg   = (float*)(ws);                         // [2048,3072] f32   25,165,824
    unsigned short* xb   = (unsigned short*)(ws + 25165824);     // [2048,1024] bf16   4,194,304
    unsigned short* hsb  = (unsigned short*)(ws + 29360128);     // [2048,1024] bf16   4,194,304
    unsigned short* wihb = (unsigned short*)(ws + 33554432);     // 6,291,456
    unsigned short* whhb = (unsigned short*)(ws + 39845888);     // 6,291,456
    unsigned short* owb  = (unsigned short*)(ws + 46137344);     // 65,536,000
    float*          hf0  = (float*)(ws + 111673344);             // 131,072
    float*          hf1  = (float*)(ws + 111804416);             // 131,072
    unsigned short* hb0  = (unsigned short*)(ws + 111935488);    // 65,536
    unsigned short* hb1  = (unsigned short*)(ws + 112001024);    // 65,536

    cast_f32_bf16<<<512, 256, 0, stream>>>(W_ih, wihb, G3 * H_);
    cast_f32_bf16<<<512, 256, 0, stream>>>(W_hh, whhb, G3 * H_);
    cast_f32_bf16<<<2048, 256, 0, stream>>>(out_W, owb, V_ * H_);
    embed_relu<<<M_, 256, 0, stream>>>(target, embedding, xb);
    init_h<<<128, 256, 0, stream>>>(enc_hidden, hf0, hb0);

    // xg = relu(emb) @ W_ih^T + b_ih
    gemm_bias<<<dim3(G3 / 128, M_ / 128), 256, 0, stream>>>(xb, wihb, b_ih, xg, G3, H_);

    // sequential GRU scan, ping-pong: step t reads buf (t&1), writes (t&1)^1
    for (int t = 0; t < T_; ++t) {
        int ri = t & 1, wi = ri ^ 1;
        gru_step_mfma<<<128, 64, 0, stream>>>(
            ri ? hb1 : hb0, ri ? hf1 : hf0,
            wi ? hb1 : hb0, wi ? hf1 : hf0,
            whhb, b_hh, xg, hsb, t);
    }
    // after t=63 (reads 1, writes 0): final h in hf0

    gemm_bias<<<dim3(V_ / 128, M_ / 128), 256, 0, stream>>>(hsb, owb, out_b, out, V_, H_);
    log_softmax_inplace<<<M_, 256, 0, stream>>>(out);
    copy_f32<<<128, 256, 0, stream>>>(hf0, out + (size_t)M_ * V_, B_ * H_);
}